// Round 7
// baseline (113.822 us; speedup 1.0000x reference)
//
#include <hip/hip_runtime.h>
#include <cmath>

namespace {

constexpr int kDim = 5;
constexpr int kSave = 64;
constexpr int kTraj = 16;      // trajectories per block (= MFMA M)
constexpr int kThreads = 256;  // 4 waves; wave w owns neuron tile [16w,16w+16)
constexpr int kMaxSteps = 64;
constexpr int ZS = 40;         // f16 stride: z rows (80 B, 16B-aligned)
constexpr int HS = 72;         // f16 stride: activation planes (144 B)
constexpr int SD = 8;          // f32 stride: scratch rows (32 B)

typedef _Float16 half8 __attribute__((ext_vector_type(8)));
typedef float f32x4 __attribute__((ext_vector_type(4)));

__device__ __forceinline__ float softplusf(float x) {
  return fmaxf(x, 0.0f) + __logf(1.0f + __expf(-fabsf(x)));
}

// order this wave's own LDS writes before its subsequent reads (no rendezvous);
// used ONLY in the once-per-step tail, never in the evalF hot path
__device__ __forceinline__ void lds_fence() {
  asm volatile("s_waitcnt lgkmcnt(0)" ::: "memory");
}

__global__ __launch_bounds__(kThreads, 1)
void node_tsit5_kernel(const float* __restrict__ gy0,
                       const float* __restrict__ gte,
                       const float* __restrict__ gW1, const float* __restrict__ gb1,
                       const float* __restrict__ gW2, const float* __restrict__ gb2,
                       const float* __restrict__ gW3, const float* __restrict__ gb3,
                       const float* __restrict__ gW4, const float* __restrict__ gb4,
                       float* __restrict__ out) {
  const float A21 = 0.161f;
  const float A31 = -0.008480655492356989f, A32 = 0.335480655492357f;
  const float A41 = 2.8971530571054935f, A42 = -6.359448489975075f, A43 = 4.3622954328695815f;
  const float A51 = 5.325864828439257f, A52 = -11.748883564062828f, A53 = 7.4955393428898365f,
              A54 = -0.09249506636175525f;
  const float A61 = 5.86145544294642f, A62 = -12.92096931784711f, A63 = 8.159367898576159f,
              A64 = -0.071584973281401f, A65 = -0.028269050394068383f;
  const float B1 = 0.09646076681806523f, B2 = 0.01f, B3 = 0.4798896504144996f,
              B4 = 1.379008574103742f, B5 = -3.290069515436081f, B6 = 2.324710524099774f;
  const float E1 = -0.00178001105222577714f, E2 = -0.0008164344596567469f,
              E3 = 0.007880878010261995f, E4 = -0.1447110071732629f, E5 = 0.5823571654525552f,
              E6 = -0.45808210592918697f, E7 = 0.015151515151515152f;

  // ---- LDS: evalF path identical to R4 (shared zb + 3-buffer hi/lo chain) ----
  __shared__ __align__(16) _Float16 zb[kTraj * ZS];    // L1 A input: [zhi(0..4)|zlo(5..9)|0]
  __shared__ __align__(16) _Float16 h0[kTraj * HS], l0[kTraj * HS];
  __shared__ __align__(16) _Float16 h1[kTraj * HS], l1[kTraj * HS];
  __shared__ __align__(16) _Float16 h2[kTraj * HS], l2[kTraj * HS];
  // wave-private interp scratch (fence-ordered, intra-wave only)
  __shared__ __align__(16) float ySs[4][kTraj * SD], ynS[4][kTraj * SD];
  __shared__ __align__(16) float k1S[4][kTraj * SD], k7S[4][kTraj * SD];
  __shared__ float ctT[4][kTraj], ctH[4][kTraj], ctN[4][kTraj], ctO[4][kTraj];

  const int tid = threadIdx.x;
  const int bid = blockIdx.x;
  const int w = tid >> 6;          // wave id = neuron tile
  const int ln = tid & 63;
  const int quad = ln >> 4;
  const int col = ln & 15;
  const int row0 = quad * 4;       // this lane's C-layout trajectories: row0+r
  const int nn = (w << 4) | col;
  const bool cact = col < kDim;    // C-lane carries dim d = col
  const bool w0 = (w == 0);

  // ---- one-time: weight B-frags + biases (exactly R4) ----
  half8 w1c, w2h[2], w3h[2], w4h[2];
  #pragma unroll
  for (int j = 0; j < 8; ++j) {
    int kk2 = quad * 8 + j;
    float wv = 0.0f;
    if (kk2 < 5) wv = gW1[nn * 5 + kk2];            // vs zhi
    else if (kk2 < 10) wv = gW1[nn * 5 + (kk2 - 5)]; // vs zlo
    w1c[j] = (_Float16)wv;
  }
  #pragma unroll
  for (int kf = 0; kf < 2; ++kf)
    #pragma unroll
    for (int j = 0; j < 8; ++j) {
      int kk2 = kf * 32 + quad * 8 + j;
      w2h[kf][j] = (_Float16)gW2[nn * 64 + kk2];
      w3h[kf][j] = (_Float16)gW3[nn * 64 + kk2];
      w4h[kf][j] = cact ? (_Float16)gW4[col * 64 + kk2] : (_Float16)0.0f;
    }
  const float c1 = gb1[nn], c2 = gb2[nn], c3 = gb3[nn];
  const float c4 = cact ? gb4[col] : 0.0f;   // => L4 cols>=5 are exactly 0

  const float t0v = gte[0];
  const float t1v = gte[kSave - 1];
  float teq[4];                                // saves handled by this lane
  #pragma unroll
  for (int q = 0; q < 4; ++q) teq[q] = gte[16 * w + 4 * quad + q];

  // ---- init: zero zb pad, then (barrier) y0 into zb — fixes R4's init race ----
  for (int i = tid; i < kTraj * ZS; i += kThreads) zb[i] = (_Float16)0.0f;
  __syncthreads();

  f32x4 syr = {0, 0, 0, 0}, synr = {0, 0, 0, 0}, kk[7];
  if (cact) {
    #pragma unroll
    for (int r = 0; r < 4; ++r) {
      float v = gy0[(size_t)(bid * kTraj + row0 + r) * kDim + col];
      syr[r] = v;
      ySs[w][(row0 + r) * SD + col] = v;     // per-wave copy for y0-fill below
      if (w0) {
        _Float16 hi = (_Float16)v;
        zb[(row0 + r) * ZS + col] = hi;
        zb[(row0 + r) * ZS + col + 5] = (_Float16)(v - (float)hi);
      }
    }
  }
  __syncthreads();

  // initial fill: saves <= t0 get y0, everything else 0 (out is 0xAA-poisoned).
  // Same (tt,n) lane later interp-writes -> program order, no race.
  {
    int tt = ln & 15;
    float y0v[kDim];
    #pragma unroll
    for (int d = 0; d < kDim; ++d) y0v[d] = ySs[w][tt * SD + d];
    #pragma unroll
    for (int q = 0; q < 4; ++q) {
      int n = 16 * w + 4 * quad + q;
      bool isy0 = teq[q] <= t0v + 1e-6f;
      float* op = out + ((size_t)(bid * kTraj + tt) * kSave + n) * kDim;
      #pragma unroll
      for (int d = 0; d < kDim; ++d) op[d] = isy0 ? y0v[d] : 0.0f;
    }
  }

  // ---- MLP: zb -> C-layout f32x4 (cols>=5 exactly 0); EXACT R4 hot path ----
  auto evalF = [&]() -> f32x4 {
    {  // L1: 5 -> 64 via K=32 packing [zhi|zlo]
      half8 az = *(const half8*)(zb + col * ZS + quad * 8);
      f32x4 a = {c1, c1, c1, c1};
      a = __builtin_amdgcn_mfma_f32_16x16x32_f16(az, w1c, a, 0, 0, 0);
      #pragma unroll
      for (int r = 0; r < 4; ++r) {
        float s = softplusf(a[r]);
        _Float16 hi = (_Float16)s;
        h0[(row0 + r) * HS + nn] = hi;
        l0[(row0 + r) * HS + nn] = (_Float16)(s - (float)hi);
      }
    }
    __syncthreads();   // b1
    {  // L2: h0/l0 -> h1/l1 (split accumulators: 2-deep chains)
      half8 ah0 = *(const half8*)(h0 + col * HS + quad * 8);
      half8 ah1 = *(const half8*)(h0 + col * HS + 32 + quad * 8);
      half8 al0 = *(const half8*)(l0 + col * HS + quad * 8);
      half8 al1 = *(const half8*)(l0 + col * HS + 32 + quad * 8);
      f32x4 a = {c2, c2, c2, c2};
      f32x4 b = {0, 0, 0, 0};
      a = __builtin_amdgcn_mfma_f32_16x16x32_f16(ah0, w2h[0], a, 0, 0, 0);
      b = __builtin_amdgcn_mfma_f32_16x16x32_f16(al0, w2h[0], b, 0, 0, 0);
      a = __builtin_amdgcn_mfma_f32_16x16x32_f16(ah1, w2h[1], a, 0, 0, 0);
      b = __builtin_amdgcn_mfma_f32_16x16x32_f16(al1, w2h[1], b, 0, 0, 0);
      a += b;
      #pragma unroll
      for (int r = 0; r < 4; ++r) {
        float s = softplusf(a[r]);
        _Float16 hi = (_Float16)s;
        h1[(row0 + r) * HS + nn] = hi;
        l1[(row0 + r) * HS + nn] = (_Float16)(s - (float)hi);
      }
    }
    __syncthreads();   // b2
    {  // L3: h1/l1 -> h2/l2
      half8 ah0 = *(const half8*)(h1 + col * HS + quad * 8);
      half8 ah1 = *(const half8*)(h1 + col * HS + 32 + quad * 8);
      half8 al0 = *(const half8*)(l1 + col * HS + quad * 8);
      half8 al1 = *(const half8*)(l1 + col * HS + 32 + quad * 8);
      f32x4 a = {c3, c3, c3, c3};
      f32x4 b = {0, 0, 0, 0};
      a = __builtin_amdgcn_mfma_f32_16x16x32_f16(ah0, w3h[0], a, 0, 0, 0);
      b = __builtin_amdgcn_mfma_f32_16x16x32_f16(al0, w3h[0], b, 0, 0, 0);
      a = __builtin_amdgcn_mfma_f32_16x16x32_f16(ah1, w3h[1], a, 0, 0, 0);
      b = __builtin_amdgcn_mfma_f32_16x16x32_f16(al1, w3h[1], b, 0, 0, 0);
      a += b;
      #pragma unroll
      for (int r = 0; r < 4; ++r) {
        float s = softplusf(a[r]);
        _Float16 hi = (_Float16)s;
        h2[(row0 + r) * HS + nn] = hi;
        l2[(row0 + r) * HS + nn] = (_Float16)(s - (float)hi);
      }
    }
    __syncthreads();   // b3
    // L4: redundantly computed by every wave (identical values)
    f32x4 a = {c4, c4, c4, c4};
    {
      half8 ah0 = *(const half8*)(h2 + col * HS + quad * 8);
      half8 ah1 = *(const half8*)(h2 + col * HS + 32 + quad * 8);
      half8 al0 = *(const half8*)(l2 + col * HS + quad * 8);
      half8 al1 = *(const half8*)(l2 + col * HS + 32 + quad * 8);
      f32x4 b = {0, 0, 0, 0};
      a = __builtin_amdgcn_mfma_f32_16x16x32_f16(ah0, w4h[0], a, 0, 0, 0);
      b = __builtin_amdgcn_mfma_f32_16x16x32_f16(al0, w4h[0], b, 0, 0, 0);
      a = __builtin_amdgcn_mfma_f32_16x16x32_f16(ah1, w4h[1], a, 0, 0, 0);
      b = __builtin_amdgcn_mfma_f32_16x16x32_f16(al1, w4h[1], b, 0, 0, 0);
      a += b;
    }
    return a;
  };

  // z (identical in all waves) -> shared zb; w0 writes + barrier (EXACT R4)
  auto zwrite = [&](f32x4 z) {
    if (w0 && cact) {
      #pragma unroll
      for (int r = 0; r < 4; ++r) {
        _Float16 hi = (_Float16)z[r];
        zb[(row0 + r) * ZS + col] = hi;
        zb[(row0 + r) * ZS + col + 5] = (_Float16)(z[r] - (float)hi);
      }
    }
    __syncthreads();
  };

  kk[0] = evalF();   // k1 = f(y0); FSAL thereafter

  // per-lane control state for trajectories row0+r (replicated across the
  // 16-lane group and across waves -> identical everywhere, bit-for-bit)
  f32x4 tcur = {t0v, t0v, t0v, t0v};
  f32x4 hcur = {0.1f, 0.1f, 0.1f, 0.1f};

  for (int step = 0; step < kMaxSteps; ++step) {
    f32x4 hcs, tOldr;
    bool dnr[4];
    bool all4 = true;
    #pragma unroll
    for (int r = 0; r < 4; ++r) {
      bool d = tcur[r] >= t1v - 1e-6f;
      dnr[r] = d;
      all4 &= d;
      hcs[r] = d ? 0.0f : fminf(hcur[r], t1v - tcur[r]);
      tOldr[r] = tcur[r];
    }
    if (__ballot(all4) == ~0ull) break;   // all 16 trajectories done

    f32x4 z;
    #pragma unroll
    for (int r = 0; r < 4; ++r) z[r] = fmaf(hcs[r], A21 * kk[0][r], syr[r]);
    zwrite(z); kk[1] = evalF();

    #pragma unroll
    for (int r = 0; r < 4; ++r)
      z[r] = fmaf(hcs[r], fmaf(A32, kk[1][r], A31 * kk[0][r]), syr[r]);
    zwrite(z); kk[2] = evalF();

    #pragma unroll
    for (int r = 0; r < 4; ++r)
      z[r] = fmaf(hcs[r], fmaf(A43, kk[2][r], fmaf(A42, kk[1][r], A41 * kk[0][r])), syr[r]);
    zwrite(z); kk[3] = evalF();

    #pragma unroll
    for (int r = 0; r < 4; ++r)
      z[r] = fmaf(hcs[r], fmaf(A54, kk[3][r], fmaf(A53, kk[2][r],
                  fmaf(A52, kk[1][r], A51 * kk[0][r]))), syr[r]);
    zwrite(z); kk[4] = evalF();

    #pragma unroll
    for (int r = 0; r < 4; ++r)
      z[r] = fmaf(hcs[r], fmaf(A65, kk[4][r], fmaf(A64, kk[3][r], fmaf(A63, kk[2][r],
                  fmaf(A62, kk[1][r], A61 * kk[0][r])))), syr[r]);
    zwrite(z); kk[5] = evalF();

    #pragma unroll
    for (int r = 0; r < 4; ++r)
      synr[r] = fmaf(hcs[r], fmaf(B6, kk[5][r], fmaf(B5, kk[4][r], fmaf(B4, kk[3][r],
                 fmaf(B3, kk[2][r], fmaf(B2, kk[1][r], B1 * kk[0][r]))))), syr[r]);
    zwrite(synr); kk[6] = evalF();   // k7 (FSAL)

    // ---- error: per-lane rr^2, gather dims 0..4 via shuffle, sum in R4's
    //      exact d=0..4 order -> bit-identical enorm to R4 ----
    f32x4 rr2;
    #pragma unroll
    for (int r = 0; r < 4; ++r) {
      float err = hcs[r] * fmaf(E7, kk[6][r], fmaf(E6, kk[5][r], fmaf(E5, kk[4][r],
                  fmaf(E4, kk[3][r], fmaf(E3, kk[2][r], fmaf(E2, kk[1][r], E1 * kk[0][r]))))));
      float sc = fmaf(1e-3f, fmaxf(fabsf(syr[r]), fabsf(synr[r])), 1e-6f);
      float rr = err / sc;
      rr2[r] = cact ? rr * rr : 0.0f;
    }
    bool okr[4];
    #pragma unroll
    for (int r = 0; r < 4; ++r) {
      float s = 0.0f;
      #pragma unroll
      for (int d = 0; d < kDim; ++d)
        s += __shfl(rr2[r], quad * 16 + d, 64);   // rr^2(traj=row0+r, dim=d)
      float enorm = sqrtf(s / 5.0f);               // EXACT R4 controller math
      float enc = fmaxf(enorm, 1e-10f);
      bool accept = enorm <= 1.0f;
      float factor = fminf(fmaxf(0.9f * powf(enc, -0.2f), 0.2f), 10.0f);
      bool ok = accept && !dnr[r];
      okr[r] = ok;
      tcur[r] = ok ? tcur[r] + hcs[r] : tcur[r];
      hcur[r] = dnr[r] ? hcur[r] : hcs[r] * factor;
    }

    // ---- stash interp state in wave-private scratch (single fence) ----
    if (cact) {
      #pragma unroll
      for (int r = 0; r < 4; ++r) {
        int o = (row0 + r) * SD + col;
        ySs[w][o] = syr[r];
        ynS[w][o] = synr[r];
        k1S[w][o] = kk[0][r];
        k7S[w][o] = kk[6][r];
      }
    }
    if (col == 0) {
      #pragma unroll
      for (int r = 0; r < 4; ++r) {
        int m = row0 + r;
        ctT[w][m] = tOldr[r];
        ctH[w][m] = hcs[r];
        ctN[w][m] = tcur[r];
        ctO[w][m] = okr[r] ? 1.0f : 0.0f;
      }
    }
    lds_fence();

    // ---- cubic Hermite interp: wave w covers saves [16w,16w+16) ----
    {
      int tt = ln & 15;
      if (ctO[w][tt] != 0.0f) {
        float tOld = ctT[w][tt], hcv = ctH[w][tt], tNew = ctN[w][tt];
        float inv = 1.0f / fmaxf(hcv, 1e-12f);
        const float* yb = &ySs[w][tt * SD];
        const float* nb = &ynS[w][tt * SD];
        const float* ab = &k1S[w][tt * SD];
        const float* bb = &k7S[w][tt * SD];
        float yv[kDim], ynv[kDim], k1v[kDim], k7v[kDim];
        #pragma unroll
        for (int d = 0; d < kDim; ++d) {
          yv[d] = yb[d];
          ynv[d] = nb[d];
          k1v[d] = hcv * ab[d];
          k7v[d] = hcv * bb[d];
        }
        #pragma unroll
        for (int q = 0; q < 4; ++q) {
          float te = teq[q];
          if (te > tOld && te <= tNew + 1e-6f) {
            int n = 16 * w + 4 * quad + q;
            float sx = (te - tOld) * inv;
            float s2 = sx * sx, s3 = s2 * sx;
            float h00 = 2.f * s3 - 3.f * s2 + 1.f;
            float h10 = s3 - 2.f * s2 + sx;
            float h01 = -2.f * s3 + 3.f * s2;
            float h11 = s3 - s2;
            float* op = out + ((size_t)(bid * kTraj + tt) * kSave + n) * kDim;
            #pragma unroll
            for (int d = 0; d < kDim; ++d)
              op[d] = h00 * yv[d] + h10 * k1v[d] + h01 * ynv[d] + h11 * k7v[d];
          }
        }
      }
    }

    // ---- FSAL + state update (registers only) ----
    #pragma unroll
    for (int r = 0; r < 4; ++r) {
      if (okr[r]) { syr[r] = synr[r]; kk[0][r] = kk[6][r]; }
    }
  }
}

}  // namespace

extern "C" void kernel_launch(void* const* d_in, const int* in_sizes, int n_in,
                              void* d_out, int out_size, void* d_ws, size_t ws_size,
                              hipStream_t stream) {
  const float* y0 = (const float*)d_in[0];
  const float* te = (const float*)d_in[1];
  const float* W1 = (const float*)d_in[2];
  const float* b1 = (const float*)d_in[3];
  const float* W2 = (const float*)d_in[4];
  const float* b2 = (const float*)d_in[5];
  const float* W3 = (const float*)d_in[6];
  const float* b3 = (const float*)d_in[7];
  const float* W4 = (const float*)d_in[8];
  const float* b4 = (const float*)d_in[9];
  float* out = (float*)d_out;

  const int batch = in_sizes[0] / kDim;      // 4096
  const int blocks = batch / kTraj;          // 256 blocks x 4 waves = 1 block/CU
  hipLaunchKernelGGL(node_tsit5_kernel, dim3(blocks), dim3(kThreads), 0, stream,
                     y0, te, W1, b1, W2, b2, W3, b3, W4, b4, out);
}

// Round 8
// 111.035 us; speedup vs baseline: 1.0251x; 1.0251x over previous
//
#include <hip/hip_runtime.h>
#include <cmath>

namespace {

constexpr int kDim = 5;
constexpr int kSave = 64;
constexpr int kTraj = 16;      // trajectories per block (= MFMA M)
constexpr int kThreads = 256;  // 4 waves; wave w owns neuron tile [16w,16w+16)
constexpr int kMaxSteps = 64;
constexpr int ZS = 40;         // f16 stride: z rows (80 B, 16B-aligned)
constexpr int HS = 72;         // f16 stride: activation planes (144 B)
constexpr int SD = 8;          // f32 stride: small state rows

typedef _Float16 half8 __attribute__((ext_vector_type(8)));
typedef float f32x4 __attribute__((ext_vector_type(4)));

__device__ __forceinline__ float softplusf(float x) {
  return fmaxf(x, 0.0f) + __logf(1.0f + __expf(-fabsf(x)));
}

__global__ __launch_bounds__(kThreads, 1)
void node_tsit5_kernel(const float* __restrict__ gy0,
                       const float* __restrict__ gte,
                       const float* __restrict__ gW1, const float* __restrict__ gb1,
                       const float* __restrict__ gW2, const float* __restrict__ gb2,
                       const float* __restrict__ gW3, const float* __restrict__ gb3,
                       const float* __restrict__ gW4, const float* __restrict__ gb4,
                       float* __restrict__ out) {
  const float A21 = 0.161f;
  const float A31 = -0.008480655492356989f, A32 = 0.335480655492357f;
  const float A41 = 2.8971530571054935f, A42 = -6.359448489975075f, A43 = 4.3622954328695815f;
  const float A51 = 5.325864828439257f, A52 = -11.748883564062828f, A53 = 7.4955393428898365f,
              A54 = -0.09249506636175525f;
  const float A61 = 5.86145544294642f, A62 = -12.92096931784711f, A63 = 8.159367898576159f,
              A64 = -0.071584973281401f, A65 = -0.028269050394068383f;
  const float B1 = 0.09646076681806523f, B2 = 0.01f, B3 = 0.4798896504144996f,
              B4 = 1.379008574103742f, B5 = -3.290069515436081f, B6 = 2.324710524099774f;
  const float E1 = -0.00178001105222577714f, E2 = -0.0008164344596567469f,
              E3 = 0.007880878010261995f, E4 = -0.1447110071732629f, E5 = 0.5823571654525552f,
              E6 = -0.45808210592918697f, E7 = 0.015151515151515152f;

  // zbp: PER-WAVE private z input (A-layout, [zhi(0..4)|zlo(5..9)|0-pad]).
  // Written and read only by the owning wave -> intra-wave DS program order
  // replaces the R4 zwrite barrier. h/l planes remain cross-wave (3 barriers).
  __shared__ __align__(16) _Float16 zbp[4][kTraj * ZS];
  __shared__ __align__(16) _Float16 h0[kTraj * HS], l0[kTraj * HS];
  __shared__ __align__(16) _Float16 h1[kTraj * HS], l1[kTraj * HS];
  __shared__ __align__(16) _Float16 h2[kTraj * HS], l2[kTraj * HS];
  __shared__ float sTe[kSave];
  __shared__ float sY[kTraj * SD], sYN[kTraj * SD], sK1[kTraj * SD], sK7[kTraj * SD];
  __shared__ float sesq[kTraj * SD];
  __shared__ float s_hc[kTraj], s_tOld[kTraj], s_tn[kTraj];
  __shared__ int s_ok[kTraj], s_done[kTraj];

  const int tid = threadIdx.x;
  const int bid = blockIdx.x;
  const int w = tid >> 6;          // wave id = neuron tile
  const int ln = tid & 63;
  const int quad = ln >> 4;
  const int col = ln & 15;
  const int row0 = quad * 4;       // this lane's C-layout trajectories: row0+r
  const int nn = (w << 4) | col;
  const bool cact = col < kDim;    // C-lane carries dim d = col
  const bool w0 = (w == 0);

  // ---- one-time: weight B-frags + biases (exactly R4) ----
  half8 w1c, w2h[2], w3h[2], w4h[2];
  #pragma unroll
  for (int j = 0; j < 8; ++j) {
    int kk2 = quad * 8 + j;
    float wv = 0.0f;
    if (kk2 < 5) wv = gW1[nn * 5 + kk2];            // vs zhi
    else if (kk2 < 10) wv = gW1[nn * 5 + (kk2 - 5)]; // vs zlo
    w1c[j] = (_Float16)wv;
  }
  #pragma unroll
  for (int kf = 0; kf < 2; ++kf)
    #pragma unroll
    for (int j = 0; j < 8; ++j) {
      int kk2 = kf * 32 + quad * 8 + j;
      w2h[kf][j] = (_Float16)gW2[nn * 64 + kk2];
      w3h[kf][j] = (_Float16)gW3[nn * 64 + kk2];
      w4h[kf][j] = cact ? (_Float16)gW4[col * 64 + kk2] : (_Float16)0.0f;
    }
  const float c1 = gb1[nn], c2 = gb2[nn], c3 = gb3[nn];
  const float c4 = cact ? gb4[col] : 0.0f;   // => L4 cols>=5 are exactly 0

  // ---- init LDS ----
  // this wave's private z plane: zero pad then y0 (same wave -> ordered)
  for (int i = ln; i < kTraj * ZS; i += 64) zbp[w][i] = (_Float16)0.0f;
  if (tid < kSave) sTe[tid] = gte[tid];
  if (tid < kTraj * kDim) {   // shared sY for interp / y0-fill
    int t = tid & 15, d = tid >> 4;
    sY[t * SD + d] = gy0[(size_t)(bid * kTraj + t) * kDim + d];
  }
  {
    float* ob = out + (size_t)bid * kTraj * kSave * kDim;
    for (int idx = tid; idx < kTraj * kSave * kDim; idx += kThreads) ob[idx] = 0.0f;
  }

  // y-state in registers, replicated in every wave; also seed private zbp
  f32x4 syr = {0, 0, 0, 0}, synr = {0, 0, 0, 0}, kk[7];
  if (cact) {
    #pragma unroll
    for (int r = 0; r < 4; ++r) {
      float v = gy0[(size_t)(bid * kTraj + row0 + r) * kDim + col];
      syr[r] = v;
      _Float16 hi = (_Float16)v;
      zbp[w][(row0 + r) * ZS + col] = hi;
      zbp[w][(row0 + r) * ZS + col + 5] = (_Float16)(v - (float)hi);
    }
  }
  __syncthreads();

  const float t0v = sTe[0];
  const float t1v = sTe[kSave - 1];

  // saves at/before t0 get y0 (same-lane overwrite later -> program order)
  {
    int tt = tid & 15, gg = tid >> 4;
    float yv[kDim];
    #pragma unroll
    for (int d = 0; d < kDim; ++d) yv[d] = sY[tt * SD + d];
    #pragma unroll
    for (int q = 0; q < 4; ++q) {
      int n = 4 * gg + q;
      if (sTe[n] <= t0v + 1e-6f) {
        float* op = out + ((size_t)(bid * kTraj + tt) * kSave + n) * kDim;
        #pragma unroll
        for (int d = 0; d < kDim; ++d) op[d] = yv[d];
      }
    }
  }

  // ---- MLP: zbp[w] -> C-layout f32x4 (cols>=5 exactly 0); 3 barriers ----
  auto evalF = [&]() -> f32x4 {
    {  // L1: 5 -> 64 via K=32 packing [zhi|zlo]; reads own wave's zbp
      half8 az = *(const half8*)(zbp[w] + col * ZS + quad * 8);
      f32x4 a = {c1, c1, c1, c1};
      a = __builtin_amdgcn_mfma_f32_16x16x32_f16(az, w1c, a, 0, 0, 0);
      #pragma unroll
      for (int r = 0; r < 4; ++r) {
        float s = softplusf(a[r]);
        _Float16 hi = (_Float16)s;
        h0[(row0 + r) * HS + nn] = hi;
        l0[(row0 + r) * HS + nn] = (_Float16)(s - (float)hi);
      }
    }
    __syncthreads();   // b1
    {  // L2: h0/l0 -> h1/l1 (split accumulators: 2-deep chains)
      half8 ah0 = *(const half8*)(h0 + col * HS + quad * 8);
      half8 ah1 = *(const half8*)(h0 + col * HS + 32 + quad * 8);
      half8 al0 = *(const half8*)(l0 + col * HS + quad * 8);
      half8 al1 = *(const half8*)(l0 + col * HS + 32 + quad * 8);
      f32x4 a = {c2, c2, c2, c2};
      f32x4 b = {0, 0, 0, 0};
      a = __builtin_amdgcn_mfma_f32_16x16x32_f16(ah0, w2h[0], a, 0, 0, 0);
      b = __builtin_amdgcn_mfma_f32_16x16x32_f16(al0, w2h[0], b, 0, 0, 0);
      a = __builtin_amdgcn_mfma_f32_16x16x32_f16(ah1, w2h[1], a, 0, 0, 0);
      b = __builtin_amdgcn_mfma_f32_16x16x32_f16(al1, w2h[1], b, 0, 0, 0);
      a += b;
      #pragma unroll
      for (int r = 0; r < 4; ++r) {
        float s = softplusf(a[r]);
        _Float16 hi = (_Float16)s;
        h1[(row0 + r) * HS + nn] = hi;
        l1[(row0 + r) * HS + nn] = (_Float16)(s - (float)hi);
      }
    }
    __syncthreads();   // b2
    {  // L3: h1/l1 -> h2/l2
      half8 ah0 = *(const half8*)(h1 + col * HS + quad * 8);
      half8 ah1 = *(const half8*)(h1 + col * HS + 32 + quad * 8);
      half8 al0 = *(const half8*)(l1 + col * HS + quad * 8);
      half8 al1 = *(const half8*)(l1 + col * HS + 32 + quad * 8);
      f32x4 a = {c3, c3, c3, c3};
      f32x4 b = {0, 0, 0, 0};
      a = __builtin_amdgcn_mfma_f32_16x16x32_f16(ah0, w3h[0], a, 0, 0, 0);
      b = __builtin_amdgcn_mfma_f32_16x16x32_f16(al0, w3h[0], b, 0, 0, 0);
      a = __builtin_amdgcn_mfma_f32_16x16x32_f16(ah1, w3h[1], a, 0, 0, 0);
      b = __builtin_amdgcn_mfma_f32_16x16x32_f16(al1, w3h[1], b, 0, 0, 0);
      a += b;
      #pragma unroll
      for (int r = 0; r < 4; ++r) {
        float s = softplusf(a[r]);
        _Float16 hi = (_Float16)s;
        h2[(row0 + r) * HS + nn] = hi;
        l2[(row0 + r) * HS + nn] = (_Float16)(s - (float)hi);
      }
    }
    __syncthreads();   // b3
    // L4: redundantly computed by every wave (identical values)
    f32x4 a = {c4, c4, c4, c4};
    {
      half8 ah0 = *(const half8*)(h2 + col * HS + quad * 8);
      half8 ah1 = *(const half8*)(h2 + col * HS + 32 + quad * 8);
      half8 al0 = *(const half8*)(l2 + col * HS + quad * 8);
      half8 al1 = *(const half8*)(l2 + col * HS + 32 + quad * 8);
      f32x4 b = {0, 0, 0, 0};
      a = __builtin_amdgcn_mfma_f32_16x16x32_f16(ah0, w4h[0], a, 0, 0, 0);
      b = __builtin_amdgcn_mfma_f32_16x16x32_f16(al0, w4h[0], b, 0, 0, 0);
      a = __builtin_amdgcn_mfma_f32_16x16x32_f16(ah1, w4h[1], a, 0, 0, 0);
      b = __builtin_amdgcn_mfma_f32_16x16x32_f16(al1, w4h[1], b, 0, 0, 0);
      a += b;
    }
    return a;
  };

  // z (identical in all waves) -> this wave's PRIVATE zbp. No barrier:
  // same-wave DS write->read to aliasing __shared__ addresses is ordered.
  auto zwrite = [&](f32x4 z) {
    if (cact) {
      #pragma unroll
      for (int r = 0; r < 4; ++r) {
        _Float16 hi = (_Float16)z[r];
        zbp[w][(row0 + r) * ZS + col] = hi;
        zbp[w][(row0 + r) * ZS + col + 5] = (_Float16)(z[r] - (float)hi);
      }
    }
  };

  kk[0] = evalF();   // k1 = f(y0); FSAL thereafter

  // per-lane control state (lanes ln<16 of every wave, identical bit-for-bit)
  float tcur = t0v, hcur = 0.1f;

  for (int step = 0; step < kMaxSteps; ++step) {
    if (ln < kTraj) {
      int dn = tcur >= t1v - 1e-6f;
      float hc = dn ? 0.0f : fminf(hcur, t1v - tcur);
      if (w0) { s_done[ln] = dn; s_hc[ln] = hc; s_tOld[ln] = tcur; }
    }
    __syncthreads();
    if (__ballot(s_done[ln & 15]) == ~0ull) break;   // uniform across waves

    f32x4 hcr;
    #pragma unroll
    for (int r = 0; r < 4; ++r) hcr[r] = s_hc[row0 + r];

    f32x4 z;
    #pragma unroll
    for (int r = 0; r < 4; ++r) z[r] = fmaf(hcr[r], A21 * kk[0][r], syr[r]);
    zwrite(z); kk[1] = evalF();

    #pragma unroll
    for (int r = 0; r < 4; ++r)
      z[r] = fmaf(hcr[r], fmaf(A32, kk[1][r], A31 * kk[0][r]), syr[r]);
    zwrite(z); kk[2] = evalF();

    #pragma unroll
    for (int r = 0; r < 4; ++r)
      z[r] = fmaf(hcr[r], fmaf(A43, kk[2][r], fmaf(A42, kk[1][r], A41 * kk[0][r])), syr[r]);
    zwrite(z); kk[3] = evalF();

    #pragma unroll
    for (int r = 0; r < 4; ++r)
      z[r] = fmaf(hcr[r], fmaf(A54, kk[3][r], fmaf(A53, kk[2][r],
                  fmaf(A52, kk[1][r], A51 * kk[0][r]))), syr[r]);
    zwrite(z); kk[4] = evalF();

    #pragma unroll
    for (int r = 0; r < 4; ++r)
      z[r] = fmaf(hcr[r], fmaf(A65, kk[4][r], fmaf(A64, kk[3][r], fmaf(A63, kk[2][r],
                  fmaf(A62, kk[1][r], A61 * kk[0][r])))), syr[r]);
    zwrite(z); kk[5] = evalF();

    #pragma unroll
    for (int r = 0; r < 4; ++r)
      synr[r] = fmaf(hcr[r], fmaf(B6, kk[5][r], fmaf(B5, kk[4][r], fmaf(B4, kk[3][r],
                 fmaf(B3, kk[2][r], fmaf(B2, kk[1][r], B1 * kk[0][r]))))), syr[r]);
    zwrite(synr); kk[6] = evalF();   // k7 (FSAL)

    // error + stash interp state (wave 0 writes; old y stays in sY until interp)
    if (w0 && cact) {
      #pragma unroll
      for (int r = 0; r < 4; ++r) {
        float err = hcr[r] * fmaf(E7, kk[6][r], fmaf(E6, kk[5][r], fmaf(E5, kk[4][r],
                    fmaf(E4, kk[3][r], fmaf(E3, kk[2][r], fmaf(E2, kk[1][r], E1 * kk[0][r]))))));
        float sc = fmaf(1e-3f, fmaxf(fabsf(syr[r]), fabsf(synr[r])), 1e-6f);
        float rr = err / sc;
        int o = (row0 + r) * SD + col;
        sesq[o] = rr * rr;
        sYN[o] = synr[r];
        sK1[o] = kk[0][r];
        sK7[o] = kk[6][r];
      }
    }
    __syncthreads();
    if (ln < kTraj) {   // every wave computes identical control update
      float s = 0.0f;
      #pragma unroll
      for (int d = 0; d < kDim; ++d) s += sesq[ln * SD + d];
      float enorm = sqrtf(s / 5.0f);
      float enc = fmaxf(enorm, 1e-10f);
      int accept = enorm <= 1.0f;
      float factor = fminf(fmaxf(0.9f * powf(enc, -0.2f), 0.2f), 10.0f);
      int dn = s_done[ln];
      int ok = accept && !dn;
      float hc = s_hc[ln];
      float tn = ok ? tcur + hc : tcur;
      if (w0) { s_tn[ln] = tn; s_ok[ln] = ok; }
      tcur = tn;
      hcur = dn ? hcur : hc * factor;
    }
    __syncthreads();
    // cubic Hermite interpolation for save points in (t, t_next]; 256 threads
    {
      int tt = tid & 15, gg = tid >> 4;
      if (s_ok[tt]) {
        float tOld = s_tOld[tt], hcs = s_hc[tt], tNew = s_tn[tt];
        float inv = 1.0f / fmaxf(hcs, 1e-12f);
        float yv[kDim], ynv[kDim], k1v[kDim], k7v[kDim];
        #pragma unroll
        for (int d = 0; d < kDim; ++d) {
          yv[d] = sY[tt * SD + d];
          ynv[d] = sYN[tt * SD + d];
          k1v[d] = hcs * sK1[tt * SD + d];
          k7v[d] = hcs * sK7[tt * SD + d];
        }
        #pragma unroll
        for (int q = 0; q < 4; ++q) {
          int n = 4 * gg + q;
          float te = sTe[n];
          if (te > tOld && te <= tNew + 1e-6f) {
            float sx = (te - tOld) * inv;
            float s2 = sx * sx, s3 = s2 * sx;
            float h00 = 2.f * s3 - 3.f * s2 + 1.f;
            float h10 = s3 - 2.f * s2 + sx;
            float h01 = -2.f * s3 + 3.f * s2;
            float h11 = s3 - s2;
            float* op = out + ((size_t)(bid * kTraj + tt) * kSave + n) * kDim;
            #pragma unroll
            for (int d = 0; d < kDim; ++d)
              op[d] = h00 * yv[d] + h10 * k1v[d] + h01 * ynv[d] + h11 * k7v[d];
          }
        }
      }
    }
    __syncthreads();
    // FSAL + state update (after interp consumed old sY)
    if (cact) {
      #pragma unroll
      for (int r = 0; r < 4; ++r) {
        int ok = s_ok[row0 + r];
        syr[r] = ok ? synr[r] : syr[r];
        kk[0][r] = ok ? kk[6][r] : kk[0][r];
        if (w0) sY[(row0 + r) * SD + col] = syr[r];
      }
    }
    __syncthreads();
  }
}

}  // namespace

extern "C" void kernel_launch(void* const* d_in, const int* in_sizes, int n_in,
                              void* d_out, int out_size, void* d_ws, size_t ws_size,
                              hipStream_t stream) {
  const float* y0 = (const float*)d_in[0];
  const float* te = (const float*)d_in[1];
  const float* W1 = (const float*)d_in[2];
  const float* b1 = (const float*)d_in[3];
  const float* W2 = (const float*)d_in[4];
  const float* b2 = (const float*)d_in[5];
  const float* W3 = (const float*)d_in[6];
  const float* b3 = (const float*)d_in[7];
  const float* W4 = (const float*)d_in[8];
  const float* b4 = (const float*)d_in[9];
  float* out = (float*)d_out;

  const int batch = in_sizes[0] / kDim;      // 4096
  const int blocks = batch / kTraj;          // 256 blocks x 4 waves = 1 block/CU
  hipLaunchKernelGGL(node_tsit5_kernel, dim3(blocks), dim3(kThreads), 0, stream,
                     y0, te, W1, b1, W2, b2, W3, b3, W4, b4, out);
}

// Round 9
// 107.770 us; speedup vs baseline: 1.0562x; 1.0303x over previous
//
#include <hip/hip_runtime.h>
#include <cmath>

namespace {

constexpr int kDim = 5;
constexpr int kSave = 64;
constexpr int kTraj = 16;      // trajectories per block (= MFMA M)
constexpr int kThreads = 256;  // 4 waves; wave w owns neuron tile [16w,16w+16)
constexpr int kMaxSteps = 64;
constexpr int HS = 72;         // f16 stride: activation planes (144 B)
constexpr int SD = 8;          // f32 stride: small state rows

typedef _Float16 half8 __attribute__((ext_vector_type(8)));
typedef float f32x4 __attribute__((ext_vector_type(4)));

__device__ __forceinline__ float softplusf(float x) {
  return fmaxf(x, 0.0f) + __logf(1.0f + __expf(-fabsf(x)));
}

__global__ __launch_bounds__(kThreads, 1)
void node_tsit5_kernel(const float* __restrict__ gy0,
                       const float* __restrict__ gte,
                       const float* __restrict__ gW1, const float* __restrict__ gb1,
                       const float* __restrict__ gW2, const float* __restrict__ gb2,
                       const float* __restrict__ gW3, const float* __restrict__ gb3,
                       const float* __restrict__ gW4, const float* __restrict__ gb4,
                       float* __restrict__ out) {
  const float A21 = 0.161f;
  const float A31 = -0.008480655492356989f, A32 = 0.335480655492357f;
  const float A41 = 2.8971530571054935f, A42 = -6.359448489975075f, A43 = 4.3622954328695815f;
  const float A51 = 5.325864828439257f, A52 = -11.748883564062828f, A53 = 7.4955393428898365f,
              A54 = -0.09249506636175525f;
  const float A61 = 5.86145544294642f, A62 = -12.92096931784711f, A63 = 8.159367898576159f,
              A64 = -0.071584973281401f, A65 = -0.028269050394068383f;
  const float B1 = 0.09646076681806523f, B2 = 0.01f, B3 = 0.4798896504144996f,
              B4 = 1.379008574103742f, B5 = -3.290069515436081f, B6 = 2.324710524099774f;
  const float E1 = -0.00178001105222577714f, E2 = -0.0008164344596567469f,
              E3 = 0.007880878010261995f, E4 = -0.1447110071732629f, E5 = 0.5823571654525552f,
              E6 = -0.45808210592918697f, E7 = 0.015151515151515152f;

  // Activation rotation h0->h1->h2; each buffer's write is >=2 barriers after
  // its previous read, so 3 barriers/eval suffice. L1 is FUSED: the next
  // eval's L1 pre-activation lives in registers (p_y + hc*sum(a_i*u_i)),
  // u_i = (W1*W4)*h3_i + W1*b4 computed in the final MFMA stage via M-frags.
  __shared__ __align__(16) _Float16 h0[kTraj * HS], l0[kTraj * HS];
  __shared__ __align__(16) _Float16 h1[kTraj * HS], l1[kTraj * HS];
  __shared__ __align__(16) _Float16 h2[kTraj * HS], l2[kTraj * HS];
  __shared__ float sTe[kSave];
  __shared__ float sY[kTraj * SD], sYN[kTraj * SD], sK1[kTraj * SD], sK7[kTraj * SD];
  __shared__ float sesq[kTraj * SD];
  __shared__ float s_hc[kTraj], s_tOld[kTraj], s_tn[kTraj];
  __shared__ int s_ok[kTraj], s_done[kTraj];

  const int tid = threadIdx.x;
  const int bid = blockIdx.x;
  const int w = tid >> 6;          // wave id = neuron tile
  const int ln = tid & 63;
  const int quad = ln >> 4;
  const int col = ln & 15;
  const int row0 = quad * 4;       // this lane's C-layout trajectories: row0+r
  const int nn = (w << 4) | col;
  const bool cact = col < kDim;    // C-lane carries dim d = col
  const bool w0 = (w == 0);

  // ---- one-time: weight B-frags + biases ----
  half8 w2h[2], w3h[2], w4h[2], mfh[2];
  float w1r[kDim];
  #pragma unroll
  for (int d = 0; d < kDim; ++d) w1r[d] = gW1[nn * 5 + d];
  #pragma unroll
  for (int kf = 0; kf < 2; ++kf)
    #pragma unroll
    for (int j = 0; j < 8; ++j) {
      int kk2 = kf * 32 + quad * 8 + j;
      w2h[kf][j] = (_Float16)gW2[nn * 64 + kk2];
      w3h[kf][j] = (_Float16)gW3[nn * 64 + kk2];
      w4h[kf][j] = cact ? (_Float16)gW4[col * 64 + kk2] : (_Float16)0.0f;
      // M[n][k] = sum_d W1[n][d] * W4[d][k]  (fused L4->L1 matrix)
      float m = 0.0f;
      #pragma unroll
      for (int d = 0; d < kDim; ++d) m = fmaf(w1r[d], gW4[d * 64 + kk2], m);
      mfh[kf][j] = (_Float16)m;
    }
  const float c1 = gb1[nn], c2 = gb2[nn], c3 = gb3[nn];
  const float c4 = cact ? gb4[col] : 0.0f;   // => k cols>=5 are exactly 0
  float cu = 0.0f;                            // (W1*b4)[nn]
  #pragma unroll
  for (int d = 0; d < kDim; ++d) cu = fmaf(w1r[d], gb4[d], cu);

  // ---- init LDS ----
  if (tid < kSave) sTe[tid] = gte[tid];
  if (tid < kTraj * kDim) {   // shared sY for interp / y0-fill
    int t = tid & 15, d = tid >> 4;
    sY[t * SD + d] = gy0[(size_t)(bid * kTraj + t) * kDim + d];
  }
  {
    float* ob = out + (size_t)bid * kTraj * kSave * kDim;
    for (int idx = tid; idx < kTraj * kSave * kDim; idx += kThreads) ob[idx] = 0.0f;
  }

  // y-state (replicated across waves) + p_y = W1*y + b1 (per wave tile, f32)
  f32x4 syr = {0, 0, 0, 0}, synr = {0, 0, 0, 0}, kk[7], uu[7], p_y;
  #pragma unroll
  for (int r = 0; r < 4; ++r) {
    const float* yr = gy0 + (size_t)(bid * kTraj + row0 + r) * kDim;
    float acc = c1;
    #pragma unroll
    for (int d = 0; d < kDim; ++d) acc = fmaf(w1r[d], yr[d], acc);
    p_y[r] = acc;
    if (cact) syr[r] = yr[col];
  }
  __syncthreads();

  const float t0v = sTe[0];
  const float t1v = sTe[kSave - 1];

  // saves at/before t0 get y0 (same-lane overwrite later -> program order)
  {
    int tt = tid & 15, gg = tid >> 4;
    float yv[kDim];
    #pragma unroll
    for (int d = 0; d < kDim; ++d) yv[d] = sY[tt * SD + d];
    #pragma unroll
    for (int q = 0; q < 4; ++q) {
      int n = 4 * gg + q;
      if (sTe[n] <= t0v + 1e-6f) {
        float* op = out + ((size_t)(bid * kTraj + tt) * kSave + n) * kDim;
        #pragma unroll
        for (int d = 0; d < kDim; ++d) op[d] = yv[d];
      }
    }
  }

  // ---- fused eval: pre1 (C-regs) -> k (cols<5) and u (all cols); 3 barriers ----
  auto evalF = [&](f32x4 pre1, f32x4& kOut, f32x4& uOut) {
    // stage A (pure VALU): softplus(pre1) -> h0/l0 (A-layout split write)
    #pragma unroll
    for (int r = 0; r < 4; ++r) {
      float s = softplusf(pre1[r]);
      _Float16 hi = (_Float16)s;
      h0[(row0 + r) * HS + nn] = hi;
      l0[(row0 + r) * HS + nn] = (_Float16)(s - (float)hi);
    }
    __syncthreads();   // b1
    {  // L2: h0/l0 -> h1/l1 (split accumulators: 2-deep chains)
      half8 ah0 = *(const half8*)(h0 + col * HS + quad * 8);
      half8 ah1 = *(const half8*)(h0 + col * HS + 32 + quad * 8);
      half8 al0 = *(const half8*)(l0 + col * HS + quad * 8);
      half8 al1 = *(const half8*)(l0 + col * HS + 32 + quad * 8);
      f32x4 a = {c2, c2, c2, c2};
      f32x4 b = {0, 0, 0, 0};
      a = __builtin_amdgcn_mfma_f32_16x16x32_f16(ah0, w2h[0], a, 0, 0, 0);
      b = __builtin_amdgcn_mfma_f32_16x16x32_f16(al0, w2h[0], b, 0, 0, 0);
      a = __builtin_amdgcn_mfma_f32_16x16x32_f16(ah1, w2h[1], a, 0, 0, 0);
      b = __builtin_amdgcn_mfma_f32_16x16x32_f16(al1, w2h[1], b, 0, 0, 0);
      a += b;
      #pragma unroll
      for (int r = 0; r < 4; ++r) {
        float s = softplusf(a[r]);
        _Float16 hi = (_Float16)s;
        h1[(row0 + r) * HS + nn] = hi;
        l1[(row0 + r) * HS + nn] = (_Float16)(s - (float)hi);
      }
    }
    __syncthreads();   // b2
    {  // L3: h1/l1 -> h2/l2
      half8 ah0 = *(const half8*)(h1 + col * HS + quad * 8);
      half8 ah1 = *(const half8*)(h1 + col * HS + 32 + quad * 8);
      half8 al0 = *(const half8*)(l1 + col * HS + quad * 8);
      half8 al1 = *(const half8*)(l1 + col * HS + 32 + quad * 8);
      f32x4 a = {c3, c3, c3, c3};
      f32x4 b = {0, 0, 0, 0};
      a = __builtin_amdgcn_mfma_f32_16x16x32_f16(ah0, w3h[0], a, 0, 0, 0);
      b = __builtin_amdgcn_mfma_f32_16x16x32_f16(al0, w3h[0], b, 0, 0, 0);
      a = __builtin_amdgcn_mfma_f32_16x16x32_f16(ah1, w3h[1], a, 0, 0, 0);
      b = __builtin_amdgcn_mfma_f32_16x16x32_f16(al1, w3h[1], b, 0, 0, 0);
      a += b;
      #pragma unroll
      for (int r = 0; r < 4; ++r) {
        float s = softplusf(a[r]);
        _Float16 hi = (_Float16)s;
        h2[(row0 + r) * HS + nn] = hi;
        l2[(row0 + r) * HS + nn] = (_Float16)(s - (float)hi);
      }
    }
    __syncthreads();   // b3
    // final stage: k = W4*h3 + b4 (redundant all waves, cols<5) and
    //              u = M*h3 + W1*b4 (this wave's 16-neuron tile, all cols)
    {
      half8 ah0 = *(const half8*)(h2 + col * HS + quad * 8);
      half8 ah1 = *(const half8*)(h2 + col * HS + 32 + quad * 8);
      half8 al0 = *(const half8*)(l2 + col * HS + quad * 8);
      half8 al1 = *(const half8*)(l2 + col * HS + 32 + quad * 8);
      f32x4 ka = {c4, c4, c4, c4};
      f32x4 kb = {0, 0, 0, 0};
      f32x4 ua = {cu, cu, cu, cu};
      f32x4 ub = {0, 0, 0, 0};
      ka = __builtin_amdgcn_mfma_f32_16x16x32_f16(ah0, w4h[0], ka, 0, 0, 0);
      kb = __builtin_amdgcn_mfma_f32_16x16x32_f16(al0, w4h[0], kb, 0, 0, 0);
      ua = __builtin_amdgcn_mfma_f32_16x16x32_f16(ah0, mfh[0], ua, 0, 0, 0);
      ub = __builtin_amdgcn_mfma_f32_16x16x32_f16(al0, mfh[0], ub, 0, 0, 0);
      ka = __builtin_amdgcn_mfma_f32_16x16x32_f16(ah1, w4h[1], ka, 0, 0, 0);
      kb = __builtin_amdgcn_mfma_f32_16x16x32_f16(al1, w4h[1], kb, 0, 0, 0);
      ua = __builtin_amdgcn_mfma_f32_16x16x32_f16(ah1, mfh[1], ua, 0, 0, 0);
      ub = __builtin_amdgcn_mfma_f32_16x16x32_f16(al1, mfh[1], ub, 0, 0, 0);
      kOut = ka + kb;
      uOut = ua + ub;
    }
  };

  evalF(p_y, kk[0], uu[0]);   // k1 = f(y0); FSAL thereafter

  float tcur = t0v, hcur = 0.1f;   // lanes ln<16 of every wave, bit-identical

  for (int step = 0; step < kMaxSteps; ++step) {
    if (ln < kTraj) {
      int dn = tcur >= t1v - 1e-6f;
      float hc = dn ? 0.0f : fminf(hcur, t1v - tcur);
      if (w0) { s_done[ln] = dn; s_hc[ln] = hc; s_tOld[ln] = tcur; }
    }
    __syncthreads();
    if (__ballot(s_done[ln & 15]) == ~0ull) break;   // uniform across waves

    f32x4 hcr;
    #pragma unroll
    for (int r = 0; r < 4; ++r) hcr[r] = s_hc[row0 + r];

    f32x4 p1;
    #pragma unroll
    for (int r = 0; r < 4; ++r) p1[r] = fmaf(hcr[r], A21 * uu[0][r], p_y[r]);
    evalF(p1, kk[1], uu[1]);

    #pragma unroll
    for (int r = 0; r < 4; ++r)
      p1[r] = fmaf(hcr[r], fmaf(A32, uu[1][r], A31 * uu[0][r]), p_y[r]);
    evalF(p1, kk[2], uu[2]);

    #pragma unroll
    for (int r = 0; r < 4; ++r)
      p1[r] = fmaf(hcr[r], fmaf(A43, uu[2][r], fmaf(A42, uu[1][r], A41 * uu[0][r])), p_y[r]);
    evalF(p1, kk[3], uu[3]);

    #pragma unroll
    for (int r = 0; r < 4; ++r)
      p1[r] = fmaf(hcr[r], fmaf(A54, uu[3][r], fmaf(A53, uu[2][r],
                  fmaf(A52, uu[1][r], A51 * uu[0][r]))), p_y[r]);
    evalF(p1, kk[4], uu[4]);

    #pragma unroll
    for (int r = 0; r < 4; ++r)
      p1[r] = fmaf(hcr[r], fmaf(A65, uu[4][r], fmaf(A64, uu[3][r], fmaf(A63, uu[2][r],
                  fmaf(A62, uu[1][r], A61 * uu[0][r])))), p_y[r]);
    evalF(p1, kk[5], uu[5]);

    f32x4 bu;
    #pragma unroll
    for (int r = 0; r < 4; ++r) {
      bu[r] = fmaf(B6, uu[5][r], fmaf(B5, uu[4][r], fmaf(B4, uu[3][r],
              fmaf(B3, uu[2][r], fmaf(B2, uu[1][r], B1 * uu[0][r])))));
      synr[r] = fmaf(hcr[r], fmaf(B6, kk[5][r], fmaf(B5, kk[4][r], fmaf(B4, kk[3][r],
                 fmaf(B3, kk[2][r], fmaf(B2, kk[1][r], B1 * kk[0][r]))))), syr[r]);
      p1[r] = fmaf(hcr[r], bu[r], p_y[r]);
    }
    evalF(p1, kk[6], uu[6]);   // k7 (FSAL)

    // error + stash interp state (wave 0 writes; old y stays in sY until interp)
    if (w0 && cact) {
      #pragma unroll
      for (int r = 0; r < 4; ++r) {
        float err = hcr[r] * fmaf(E7, kk[6][r], fmaf(E6, kk[5][r], fmaf(E5, kk[4][r],
                    fmaf(E4, kk[3][r], fmaf(E3, kk[2][r], fmaf(E2, kk[1][r], E1 * kk[0][r]))))));
        float sc = fmaf(1e-3f, fmaxf(fabsf(syr[r]), fabsf(synr[r])), 1e-6f);
        float rr = err / sc;
        int o = (row0 + r) * SD + col;
        sesq[o] = rr * rr;
        sYN[o] = synr[r];
        sK1[o] = kk[0][r];
        sK7[o] = kk[6][r];
      }
    }
    __syncthreads();
    if (ln < kTraj) {   // every wave computes identical control update
      float s = 0.0f;
      #pragma unroll
      for (int d = 0; d < kDim; ++d) s += sesq[ln * SD + d];
      float enorm = sqrtf(s / 5.0f);
      float enc = fmaxf(enorm, 1e-10f);
      int accept = enorm <= 1.0f;
      float factor = fminf(fmaxf(0.9f * powf(enc, -0.2f), 0.2f), 10.0f);
      int dn = s_done[ln];
      int ok = accept && !dn;
      float hc = s_hc[ln];
      float tn = ok ? tcur + hc : tcur;
      if (w0) { s_tn[ln] = tn; s_ok[ln] = ok; }
      tcur = tn;
      hcur = dn ? hcur : hc * factor;
    }
    __syncthreads();
    // cubic Hermite interpolation for save points in (t, t_next]; 256 threads
    {
      int tt = tid & 15, gg = tid >> 4;
      if (s_ok[tt]) {
        float tOld = s_tOld[tt], hcs = s_hc[tt], tNew = s_tn[tt];
        float inv = 1.0f / fmaxf(hcs, 1e-12f);
        float yv[kDim], ynv[kDim], k1v[kDim], k7v[kDim];
        #pragma unroll
        for (int d = 0; d < kDim; ++d) {
          yv[d] = sY[tt * SD + d];
          ynv[d] = sYN[tt * SD + d];
          k1v[d] = hcs * sK1[tt * SD + d];
          k7v[d] = hcs * sK7[tt * SD + d];
        }
        #pragma unroll
        for (int q = 0; q < 4; ++q) {
          int n = 4 * gg + q;
          float te = sTe[n];
          if (te > tOld && te <= tNew + 1e-6f) {
            float sx = (te - tOld) * inv;
            float s2 = sx * sx, s3 = s2 * sx;
            float h00 = 2.f * s3 - 3.f * s2 + 1.f;
            float h10 = s3 - 2.f * s2 + sx;
            float h01 = -2.f * s3 + 3.f * s2;
            float h11 = s3 - s2;
            float* op = out + ((size_t)(bid * kTraj + tt) * kSave + n) * kDim;
            #pragma unroll
            for (int d = 0; d < kDim; ++d)
              op[d] = h00 * yv[d] + h10 * k1v[d] + h01 * ynv[d] + h11 * k7v[d];
          }
        }
      }
    }
    __syncthreads();
    // FSAL + state update (after interp consumed old sY)
    #pragma unroll
    for (int r = 0; r < 4; ++r) {
      int ok = s_ok[row0 + r];
      if (ok) {
        syr[r] = synr[r];
        kk[0][r] = kk[6][r];
        uu[0][r] = uu[6][r];
        p_y[r] = fmaf(hcr[r], bu[r], p_y[r]);   // p_ynew = W1*ynew + b1 (recursed)
      }
      if (w0 && cact) sY[(row0 + r) * SD + col] = syr[r];
    }
    __syncthreads();
  }
}

}  // namespace

extern "C" void kernel_launch(void* const* d_in, const int* in_sizes, int n_in,
                              void* d_out, int out_size, void* d_ws, size_t ws_size,
                              hipStream_t stream) {
  const float* y0 = (const float*)d_in[0];
  const float* te = (const float*)d_in[1];
  const float* W1 = (const float*)d_in[2];
  const float* b1 = (const float*)d_in[3];
  const float* W2 = (const float*)d_in[4];
  const float* b2 = (const float*)d_in[5];
  const float* W3 = (const float*)d_in[6];
  const float* b3 = (const float*)d_in[7];
  const float* W4 = (const float*)d_in[8];
  const float* b4 = (const float*)d_in[9];
  float* out = (float*)d_out;

  const int batch = in_sizes[0] / kDim;      // 4096
  const int blocks = batch / kTraj;          // 256 blocks x 4 waves = 1 block/CU
  hipLaunchKernelGGL(node_tsit5_kernel, dim3(blocks), dim3(kThreads), 0, stream,
                     y0, te, W1, b1, W2, b2, W3, b3, W4, b4, out);
}